// Round 13
// baseline (357.943 us; speedup 1.0000x reference)
//
#include <hip/hip_runtime.h>
#include <math.h>

typedef __attribute__((ext_vector_type(8))) __bf16 bf16x8;
typedef __attribute__((ext_vector_type(4))) float f32x4;
typedef __attribute__((ext_vector_type(4))) unsigned u32x4;

__device__ __forceinline__ float act_lrelu(float x) { return x >= 0.0f ? x : 0.01f * x; }
__device__ __forceinline__ float act_gelu(float x) { return 0.5f * x * (1.0f + erff(x * 0.7071067811865475f)); }
__device__ __forceinline__ ushort f2bf(float f) {
    unsigned u = __builtin_bit_cast(unsigned, f);
    u += 0x7fffu + ((u >> 16) & 1u);   // RTNE
    return (ushort)(u >> 16);
}
__device__ __forceinline__ unsigned pack2bf(float lo, float hi) {
    return (unsigned)f2bf(lo) | ((unsigned)f2bf(hi) << 16);
}

// ---------------------------------------------------------------------------
// LDS-swizzle MFMA helpers (used by prep's Wcomb and outpath2 only).
// W LDS layout: [128][128] ushort, element (r,c) at r*128 + (c ^ ((r&7)<<3)).
__device__ __forceinline__ void layer8swz(const bf16x8 a[4], const ushort* Wl,
                                          f32x4 acc[8], int l15, int lk8)
{
    const int sx = (l15 & 7) << 3;
    #pragma unroll
    for (int ds = 0; ds < 4; ++ds) {
        const int cb = (ds * 32 + lk8) ^ sx;
        #pragma unroll
        for (int nt = 0; nt < 8; ++nt) {
            const bf16x8 b = *(const bf16x8*)&Wl[(nt * 16 + l15) * 128 + cb];
            acc[nt] = __builtin_amdgcn_mfma_f32_16x16x32_bf16(a[ds], b, acc[nt], 0, 0, 0);
        }
    }
}

template <int ACT>
__device__ __forceinline__ void retile_swz(const f32x4 acc[8], const float bias[8],
                                           ushort* tlw, int l15, int lr4, int lk8,
                                           bf16x8 aout[4])
{
    #pragma unroll
    for (int nt = 0; nt < 8; ++nt)
        #pragma unroll
        for (int j = 0; j < 4; ++j) {
            float v = acc[nt][j] + bias[nt];
            if constexpr (ACT == 1) v = act_lrelu(v);
            if constexpr (ACT == 2) v = act_gelu(v);
            const int row = lr4 + j;
            tlw[row * 128 + ((nt * 16 + l15) ^ ((row & 7) << 3))] = f2bf(v);
        }
    const int sx = (l15 & 7) << 3;
    #pragma unroll
    for (int ds = 0; ds < 4; ++ds)
        aout[ds] = *(const bf16x8*)&tlw[l15 * 128 + ((ds * 32 + lk8) ^ sx)];
}

// Fragment-order weight MFMA: Wp = Wf + lane*8; fragment (ds,nt) at
// byte offset (nt*4+ds)*1024. One coalesced 1KB load per fragment per wave.
__device__ __forceinline__ void layer8frag(const bf16x8 a[4],
                                           const ushort* __restrict__ Wp,
                                           f32x4 acc[8])
{
    #pragma unroll
    for (int ds = 0; ds < 4; ++ds)
        #pragma unroll
        for (int nt = 0; nt < 8; ++nt) {
            const bf16x8 b = *(const bf16x8*)(Wp + ((nt * 4 + ds) << 9));
            acc[nt] = __builtin_amdgcn_mfma_f32_16x16x32_bf16(a[ds], b, acc[nt], 0, 0, 0);
        }
}

// ---------------------------------------------------------------------------
// transpose helper: IN [bz][C][N] f32 tile (c0,n0) -> OUT [bz][N][C] bf16
__device__ __forceinline__ void transpose_tile(
    const float* __restrict__ IN, ushort* __restrict__ OUTb,
    int C, int N, int bx, int by, int bz, float (*T)[68], int tid)
{
    const int r = tid >> 4, c4 = (tid & 15) * 4;
    const int n0 = bx * 64, c0 = by * 64;
    const size_t ib = (size_t)bz * C * N;
    const size_t ob = (size_t)bz * N * C;
    #pragma unroll
    for (int p = 0; p < 4; ++p) {
        const int cl = r + p * 16;
        const float4 v = *(const float4*)&IN[ib + (size_t)(c0 + cl) * N + n0 + c4];
        *(float4*)&T[cl][c4] = v;
    }
    __syncthreads();
    #pragma unroll
    for (int p = 0; p < 4; ++p) {
        const int nl = r + p * 16;
        ushort4 u;
        u.x = f2bf(T[c4 + 0][nl]);
        u.y = f2bf(T[c4 + 1][nl]);
        u.z = f2bf(T[c4 + 2][nl]);
        u.w = f2bf(T[c4 + 3][nl]);
        *(ushort4*)&OUTb[ob + (size_t)(n0 + nl) * C + c0 + c4] = u;
    }
}

// ---------------------------------------------------------------------------
// prep: grid 2206, block 256.
//  blk 0..13    : fragment-order convert of 14 MLP matrices (wqc x8, wq1, wq2,
//                 wk1, wk2, wv1, wv2). Fragment (ds,nt), lane l holds
//                 W[nt*16+(l&15)][ds*32+(l>>4)*8 .. +7] at Wdst[m*16384 +
//                 (nt*4+ds)*512 + l*8].
//  blk 14..17   : wf2 row-major bf16 convert (for outpath2's staged path)
//  blk 18..145  : queryT = query^T bf16 (128 blocks)
//  blk 146..153 : Wcomb_h = wf1_h @ wo via MFMA
//  blk 154..157 : bconst[j] = bf1[j] + sum_k wf1[j][k]*bo[k&127]
//  blk 158..2205: ftb = fts^T bf16 (2048 blocks)
__global__ __launch_bounds__(256) void prep_kernel(
    const float* __restrict__ wqc, const float* __restrict__ wq1,
    const float* __restrict__ wq2, const float* __restrict__ wk1,
    const float* __restrict__ wk2, const float* __restrict__ wv1,
    const float* __restrict__ wv2, const float* __restrict__ wf2,
    const float* __restrict__ query, const float* __restrict__ fts,
    const float* __restrict__ wo, const float* __restrict__ wf1,
    const float* __restrict__ bo, const float* __restrict__ bf1,
    ushort* __restrict__ Wdst, ushort* __restrict__ queryT,
    ushort* __restrict__ ftb, ushort* __restrict__ Wcomb,
    float* __restrict__ bconst)
{
    __shared__ __align__(16) char sbuf[32768];
    const int tid = threadIdx.x;
    const int blk = blockIdx.x;

    if (blk < 14) {                       // fragment-order weight convert
        const float* s;
        if (blk < 8) s = wqc + blk * 16384;
        else s = (blk == 8) ? wq1 : (blk == 9) ? wq2 : (blk == 10) ? wk1 :
                 (blk == 11) ? wk2 : (blk == 12) ? wv1 : wv2;
        ushort* d = Wdst + blk * 16384;
        #pragma unroll
        for (int it = 0; it < 8; ++it) {
            const int o = (tid + it * 256) * 8;
            const int frag = o >> 9;
            const int ln = (o >> 3) & 63;
            const int row = (frag >> 2) * 16 + (ln & 15);
            const int col = (frag & 3) * 32 + (ln >> 4) * 8;
            const float4 lo = *(const float4*)&s[row * 128 + col];
            const float4 hi = *(const float4*)&s[row * 128 + col + 4];
            ushort4 u0, u1;
            u0.x = f2bf(lo.x); u0.y = f2bf(lo.y); u0.z = f2bf(lo.z); u0.w = f2bf(lo.w);
            u1.x = f2bf(hi.x); u1.y = f2bf(hi.y); u1.z = f2bf(hi.z); u1.w = f2bf(hi.w);
            *(ushort4*)&d[o] = u0;
            *(ushort4*)&d[o + 4] = u1;
        }
    } else if (blk < 18) {                // wf2 row-major convert
        #pragma unroll
        for (int p = 0; p < 4; ++p) {
            const int lin = (blk - 14) * 4096 + p * 1024 + tid * 4;
            const float4 v = *(const float4*)&wf2[lin];
            ushort4 u; u.x = f2bf(v.x); u.y = f2bf(v.y); u.z = f2bf(v.z); u.w = f2bf(v.w);
            *(ushort4*)&Wdst[229376 + lin] = u;
        }
    } else if (blk < 146) {               // queryT
        const int b2 = blk - 18;
        transpose_tile(query, queryT, 128, 1024, b2 & 15, (b2 >> 4) & 1, b2 >> 5,
                       (float(*)[68])sbuf, tid);
    } else if (blk < 154) {               // Wcomb via MFMA
        ushort* Wl = (ushort*)sbuf;
        const int h = blk - 146;
        const int lane = tid & 63, w = tid >> 6;
        const int l15 = lane & 15, lk8 = (lane >> 4) * 8, lr4 = (lane >> 4) * 4;
        #pragma unroll
        for (int it = 0; it < 16; ++it) {
            const int lin = (tid + it * 256) * 4;
            const int o = lin >> 7, d4 = lin & 127;
            const float4 v = *(const float4*)&wo[o * 128 + d4];
            #pragma unroll
            for (int j = 0; j < 4; ++j) {
                const int d = d4 + j;
                Wl[d * 128 + (o ^ ((d & 7) << 3))] = f2bf((&v.x)[j]);
            }
        }
        __syncthreads();
        const f32x4 z = {0.f, 0.f, 0.f, 0.f};
        #pragma unroll
        for (int rf = 0; rf < 2; ++rf) {
            const int row = w * 32 + rf * 16;
            bf16x8 a[4];
            #pragma unroll
            for (int ds = 0; ds < 4; ++ds) {
                const size_t base = (size_t)(row + l15) * 1024 + h * 128 + ds * 32 + lk8;
                const float4 lo = *(const float4*)&wf1[base];
                const float4 hi = *(const float4*)&wf1[base + 4];
                u32x4 wv;
                wv[0] = pack2bf(lo.x, lo.y); wv[1] = pack2bf(lo.z, lo.w);
                wv[2] = pack2bf(hi.x, hi.y); wv[3] = pack2bf(hi.z, hi.w);
                a[ds] = __builtin_bit_cast(bf16x8, wv);
            }
            f32x4 acc[8];
            #pragma unroll
            for (int i = 0; i < 8; ++i) acc[i] = z;
            layer8swz(a, Wl, acc, l15, lk8);
            #pragma unroll
            for (int nt = 0; nt < 8; ++nt)
                #pragma unroll
                for (int j = 0; j < 4; ++j)
                    Wcomb[h * 16384 + (row + lr4 + j) * 128 + nt * 16 + l15] =
                        f2bf(acc[nt][j]);
        }
    } else if (blk < 158) {               // bconst
        float* sm = (float*)sbuf;
        const int jl = tid >> 3, part = tid & 7;
        const int j = (blk - 154) * 32 + jl;
        float4 a4 = {0.f, 0.f, 0.f, 0.f};
        #pragma unroll
        for (int kk = 0; kk < 128; kk += 4) {
            const float4 wv = *(const float4*)&wf1[(size_t)j * 1024 + part * 128 + kk];
            const float4 bv = *(const float4*)&bo[kk];
            a4.x += wv.x * bv.x; a4.y += wv.y * bv.y;
            a4.z += wv.z * bv.z; a4.w += wv.w * bv.w;
        }
        sm[tid] = a4.x + a4.y + a4.z + a4.w;
        __syncthreads();
        if (part == 0) {
            float t = bf1[j];
            #pragma unroll
            for (int p2 = 0; p2 < 8; ++p2) t += sm[jl * 8 + p2];
            bconst[j] = t;
        }
    } else {                              // ftb
        const int b2 = blk - 158;
        transpose_tile(fts, ftb, 128, 2048, b2 & 31, (b2 >> 5) & 1, b2 >> 6,
                       (float(*)[68])sbuf, tid);
    }
}

// ---------------------------------------------------------------------------
// mlp3qfrag: fused q-path (qconv -> lrelu-MLP -> gelu-MLP), fragment weights,
// no weight LDS, no barriers. grid 256, block 256 (4 waves x 32 rows).
__global__ __launch_bounds__(256, 4) void mlp3qfrag(
    const ushort* __restrict__ Xq, const ushort* __restrict__ Wbf,
    const float* __restrict__ Bqc, const float* __restrict__ B1,
    const float* __restrict__ B2, ushort* __restrict__ Y)
{
    __shared__ ushort tl[4][16 * 128];
    const int tid = threadIdx.x, lane = tid & 63, w = tid >> 6;
    const int l15 = lane & 15, lk8 = (lane >> 4) * 8, lr4 = (lane >> 4) * 4;
    const int head = (blockIdx.x >> 3) & 7;
    const ushort* W0p = Wbf + head * 16384 + lane * 8;
    const ushort* W1p = Wbf + 131072 + lane * 8;
    const ushort* W2p = Wbf + 147456 + lane * 8;
    float b0[8], b1[8], b2[8];
    #pragma unroll
    for (int nt = 0; nt < 8; ++nt) {
        b0[nt] = Bqc[head * 128 + nt * 16 + l15];
        b1[nt] = B1[nt * 16 + l15];
        b2[nt] = B2[nt * 16 + l15];
    }
    const int m0 = blockIdx.x * 128 + w * 32;
    const f32x4 z = {0.f, 0.f, 0.f, 0.f};
    #pragma unroll
    for (int rf = 0; rf < 2; ++rf) {
        const int row = m0 + rf * 16;
        const int rq = (row >> 13) * 1024 + (row & 1023) + l15;  // queryT-space
        bf16x8 a[4];
        #pragma unroll
        for (int ds = 0; ds < 4; ++ds)
            a[ds] = *(const bf16x8*)(Xq + (size_t)rq * 128 + ds * 32 + lk8);
        f32x4 acc[8];
        #pragma unroll
        for (int i = 0; i < 8; ++i) acc[i] = z;
        layer8frag(a, W0p, acc);
        bf16x8 a1[4];
        retile_swz<0>(acc, b0, tl[w], l15, lr4, lk8, a1);
        #pragma unroll
        for (int i = 0; i < 8; ++i) acc[i] = z;
        layer8frag(a1, W1p, acc);
        bf16x8 a2[4];
        retile_swz<1>(acc, b1, tl[w], l15, lr4, lk8, a2);
        #pragma unroll
        for (int i = 0; i < 8; ++i) acc[i] = z;
        layer8frag(a2, W2p, acc);
        #pragma unroll
        for (int nt = 0; nt < 8; ++nt)
            #pragma unroll
            for (int j = 0; j < 4; ++j)
                Y[(size_t)(row + lr4 + j) * 128 + nt * 16 + l15] =
                    f2bf(act_gelu(acc[nt][j] + b2[nt]));
    }
}

// ---------------------------------------------------------------------------
// mlp2frag: Y = gelu(lrelu(X@W1^T+b1)@W2^T+b2), fragment weights, no weight
// LDS, no barriers. 128 rows/block, block 256. OUTT: transposed V write.
template <bool OUTT>
__global__ __launch_bounds__(256, 4) void mlp2frag(
    const ushort* __restrict__ X,
    const ushort* __restrict__ W1f, const float* __restrict__ B1,
    const ushort* __restrict__ W2f, const float* __restrict__ B2,
    ushort* __restrict__ Y)
{
    __shared__ ushort tl[4][16 * 128];
    const int tid = threadIdx.x, lane = tid & 63, w = tid >> 6;
    const int l15 = lane & 15, lk8 = (lane >> 4) * 8, lr4 = (lane >> 4) * 4;
    const ushort* W1p = W1f + lane * 8;
    const ushort* W2p = W2f + lane * 8;
    float b1[8], b2[8];
    #pragma unroll
    for (int nt = 0; nt < 8; ++nt) { b1[nt] = B1[nt * 16 + l15]; b2[nt] = B2[nt * 16 + l15]; }
    const int m0 = blockIdx.x * 128 + w * 32;
    const f32x4 z = {0.f, 0.f, 0.f, 0.f};
    #pragma unroll
    for (int rf = 0; rf < 2; ++rf) {
        const int row = m0 + rf * 16;
        bf16x8 a[4];
        #pragma unroll
        for (int ds = 0; ds < 4; ++ds)
            a[ds] = *(const bf16x8*)(X + (size_t)(row + l15) * 128 + ds * 32 + lk8);
        f32x4 acc[8];
        #pragma unroll
        for (int i = 0; i < 8; ++i) acc[i] = z;
        layer8frag(a, W1p, acc);
        bf16x8 a2[4];
        retile_swz<1>(acc, b1, tl[w], l15, lr4, lk8, a2);
        #pragma unroll
        for (int i = 0; i < 8; ++i) acc[i] = z;
        layer8frag(a2, W2p, acc);
        if constexpr (!OUTT) {
            #pragma unroll
            for (int nt = 0; nt < 8; ++nt)
                #pragma unroll
                for (int j = 0; j < 4; ++j)
                    Y[(size_t)(row + lr4 + j) * 128 + nt * 16 + l15] =
                        f2bf(act_gelu(acc[nt][j] + b2[nt]));
        } else {
            const int R0 = row + lr4;
            const int bh = R0 >> 11, key = R0 & 2047;
            #pragma unroll
            for (int nt = 0; nt < 8; ++nt) {
                ushort4 pk;
                #pragma unroll
                for (int j = 0; j < 4; ++j)
                    (&pk.x)[j] = f2bf(act_gelu(acc[nt][j] + b2[nt]));
                *(ushort4*)&Y[((size_t)bh * 128 + nt * 16 + l15) * 2048 + key] = pk;
            }
        }
    }
}

// ---------------------------------------------------------------------------
// outpath: y = lrelu(sum_h enh_h @ Wcomb_h^T + bconst); out = lrelu(y@wf2^T+bf2)
__global__ __launch_bounds__(128) void outpath2(
    const ushort* __restrict__ E, const ushort* __restrict__ Wcomb,
    const float* __restrict__ bconst, const ushort* __restrict__ Wf2bf,
    const float* __restrict__ Bf2, float* __restrict__ OUT)
{
    __shared__ ushort Wc[128 * 128], W2l[128 * 128];
    __shared__ ushort tl[2][16 * 128];
    const int tid = threadIdx.x, lane = tid & 63, w = tid >> 6;
    const int l15 = lane & 15, lk8 = (lane >> 4) * 8, lr4 = (lane >> 4) * 4;
    const int b = blockIdx.x >> 5;
    const int m0 = (blockIdx.x & 31) * 32;

    #pragma unroll
    for (int it = 0; it < 16; ++it) {
        const int lin = (tid + it * 128) * 8;
        const int r = lin >> 7, c = lin & 127;
        *(bf16x8*)&W2l[r * 128 + (c ^ ((r & 7) << 3))] = *(const bf16x8*)&Wf2bf[lin];
    }
    float bc[8], b2[8];
    #pragma unroll
    for (int nt = 0; nt < 8; ++nt) { bc[nt] = bconst[nt * 16 + l15]; b2[nt] = Bf2[nt * 16 + l15]; }

    const f32x4 z = {0.f, 0.f, 0.f, 0.f};
    f32x4 yacc[8];
    #pragma unroll
    for (int i = 0; i < 8; ++i) yacc[i] = z;

    bf16x8 a[4], an[4], wreg[16];
    auto loadE = [&](int h, bf16x8 dst[4]) {
        const size_t er = ((size_t)((b * 8 + h) * 1024) + m0 + w * 16 + l15) * 128;
        #pragma unroll
        for (int ds = 0; ds < 4; ++ds) dst[ds] = *(const bf16x8*)(E + er + ds * 32 + lk8);
    };
    auto wload = [&](int h) {
        #pragma unroll
        for (int it = 0; it < 16; ++it)
            wreg[it] = *(const bf16x8*)&Wcomb[h * 16384 + (tid + it * 128) * 8];
    };
    auto wwrite = [&]() {
        #pragma unroll
        for (int it = 0; it < 16; ++it) {
            const int lin = (tid + it * 128) * 8;
            const int r = lin >> 7, c = lin & 127;
            *(bf16x8*)&Wc[r * 128 + (c ^ ((r & 7) << 3))] = wreg[it];
        }
    };

    wload(0); wwrite();
    loadE(0, a);
    for (int h = 0; h < 8; ++h) {
        if (h < 7) { wload(h + 1); loadE(h + 1, an); }
        __syncthreads();
        layer8swz(a, Wc, yacc, l15, lk8);
        __syncthreads();
        if (h < 7) {
            wwrite();
            #pragma unroll
            for (int ds = 0; ds < 4; ++ds) a[ds] = an[ds];
        }
    }
    bf16x8 a3[4];
    retile_swz<1>(yacc, bc, tl[w], l15, lr4, lk8, a3);
    f32x4 oacc[8];
    #pragma unroll
    for (int i = 0; i < 8; ++i) oacc[i] = z;
    layer8swz(a3, W2l, oacc, l15, lk8);
    #pragma unroll
    for (int nt = 0; nt < 8; ++nt)
        #pragma unroll
        for (int j = 0; j < 4; ++j)
            OUT[((size_t)b * 1024 + m0 + w * 16 + lr4 + j) * 128 + nt * 16 + l15] =
                act_lrelu(oacc[nt][j] + b2[nt]);
}

// ---------------------------------------------------------------------------
// bf16 MFMA flash attention v4 (R9 version, unchanged): swapped operands,
// in-register softmax, XOR-swizzled LDS, K dbuf, V single buf, 48 KB LDS.
__global__ __launch_bounds__(256, 3) void flash_attn_bf16(
    const ushort* __restrict__ Q, const ushort* __restrict__ Kx,
    const ushort* __restrict__ Vt, ushort* __restrict__ O)
{
    constexpr float SCALE = 0.08838834764831845f;
    const int bid = blockIdx.x;
    const int bh = (bid & 7) * 4 + ((bid >> 3) & 3);
    const int m0 = (bid >> 5) * 64;
    const int tid = threadIdx.x;
    const int lane = tid & 63, w = tid >> 6;
    const int l15 = lane & 15, g = lane >> 4;
    const int lk8 = g * 8, lr4 = g * 4;
    const int sxk = (l15 & 7) << 3;
    const int sel = g >> 1;
    const int src0 = l15 + ((lane & 16) << 1);

    __shared__ ushort K_lds[2][64 * 128];
    __shared__ ushort V_lds[128 * 64];

    const ushort* Qb = Q + (size_t)bh * 1024 * 128;
    const ushort* Kb = Kx + (size_t)bh * 2048 * 128;
    const ushort* Vb = Vt + (size_t)bh * 128 * 2048;

    bf16x8 qf[4];
    {
        const int row = m0 + w * 16 + l15;
        #pragma unroll
        for (int ds = 0; ds < 4; ++ds)
            qf[ds] = *(const bf16x8*)(Qb + (size_t)row * 128 + ds * 32 + lk8);
    }

    const int kr = tid >> 4, kc = (tid & 15) * 8;
    const int vr = tid >> 3, vc = (tid & 7) * 8;
    bf16x8 kreg[4], vreg[4];
    #pragma unroll
    for (int it = 0; it < 4; ++it) {
        kreg[it] = *(const bf16x8*)(Kb + (size_t)(kr + it * 16) * 128 + kc);
        vreg[it] = *(const bf16x8*)(Vb + (size_t)(vr + it * 32) * 2048 + vc);
    }
    #pragma unroll
    for (int it = 0; it < 4; ++it) {
        const int r = kr + it * 16;
        *(bf16x8*)&K_lds[0][r * 128 + (kc ^ ((r & 7) << 3))] = kreg[it];
        const int rv = vr + it * 32;
        *(bf16x8*)&V_lds[rv * 64 + (vc ^ ((rv & 7) << 3))] = vreg[it];
    }
    __syncthreads();

    f32x4 oacc[8];
    #pragma unroll
    for (int i = 0; i < 8; ++i) oacc[i] = f32x4{0.f, 0.f, 0.f, 0.f};
    float mrun = -1e30f, lrun = 0.f;
    int cur = 0;

    for (int nt = 0; nt < 32; ++nt) {
        if (nt < 31) {
            const int n1 = (nt + 1) * 64;
            #pragma unroll
            for (int it = 0; it < 4; ++it) {
                kreg[it] = *(const bf16x8*)(Kb + (size_t)(n1 + kr + it * 16) * 128 + kc);
                vreg[it] = *(const bf16x8*)(Vb + (size_t)(vr + it * 32) * 2048 + n1 + vc);
            }
        }
        const ushort* Kc = &K_lds[cur][0];

        f32x4 s[4];
        #pragma unroll
        for (int i = 0; i < 4; ++i) s[i] = f32x4{0.f, 0.f, 0.f, 0.f};
        __builtin_amdgcn_s_setprio(1);
        #pragma unroll
        for (int ds = 0; ds < 4; ++ds)
            #pragma unroll
            for (int ct = 0; ct < 4; ++ct) {
                const bf16x8 kf = *(const bf16x8*)
                    &Kc[(ct * 16 + l15) * 128 + ((ds * 32 + lk8) ^ sxk)];
                s[ct] = __builtin_amdgcn_mfma_f32_16x16x32_bf16(kf, qf[ds], s[ct], 0, 0, 0);
            }
        __builtin_amdgcn_s_setprio(0);

        float mx = fmaxf(fmaxf(fmaxf(s[0][0], s[0][1]), fmaxf(s[0][2], s[0][3])),
                         fmaxf(fmaxf(s[1][0], s[1][1]), fmaxf(s[1][2], s[1][3])));
        mx = fmaxf(mx, fmaxf(fmaxf(fmaxf(s[2][0], s[2][1]), fmaxf(s[2][2], s[2][3])),
                             fmaxf(fmaxf(s[3][0], s[3][1]), fmaxf(s[3][2], s[3][3]))));
        mx *= SCALE;
        mx = fmaxf(mx, __shfl_xor(mx, 16));
        mx = fmaxf(mx, __shfl_xor(mx, 32));

        if (!__all((int)(mx <= mrun + 8.f))) {
            const float mnew = fmaxf(mrun, mx);
            const float fsc = __expf(mrun - mnew);
            mrun = mnew;
            lrun *= fsc;
            #pragma unroll
            for (int dt = 0; dt < 8; ++dt)
                #pragma unroll
                for (int j = 0; j < 4; ++j)
                    oacc[dt][j] *= fsc;
        }

        float p[4][4];
        float sum = 0.f;
        #pragma unroll
        for (int ct = 0; ct < 4; ++ct)
            #pragma unroll
            for (int r = 0; r < 4; ++r) {
                const float e = __expf(s[ct][r] * SCALE - mrun);
                p[ct][r] = e;
                sum += e;
            }
        sum += __shfl_xor(sum, 16);
        sum += __shfl_xor(sum, 32);
        lrun += sum;

        unsigned P2[4][2];
        #pragma unroll
        for (int ct = 0; ct < 4; ++ct) {
            P2[ct][0] = pack2bf(p[ct][0], p[ct][1]);
            P2[ct][1] = pack2bf(p[ct][2], p[ct][3]);
        }

        __builtin_amdgcn_s_setprio(1);
        #pragma unroll
        for (int ks = 0; ks < 2; ++ks) {
            u32x4 wv;
            #pragma unroll
            for (int t = 0; t < 4; ++t) {
                const int src = src0 + ((t >> 1) << 4);
                const unsigned wa = __shfl(P2[ks * 2 + 0][t & 1], src);
                const unsigned wb = __shfl(P2[ks * 2 + 1][t & 1], src);
                wv[t] = sel ? wb : wa;
            }
            const bf16x8 pa = __builtin_bit_cast(bf16x8, wv);
            #pragma unroll
            for (int dt = 0; dt < 8; ++dt) {
                const int rv = dt * 16 + l15;
                const bf16x8 vb = *(const bf16x8*)
                    &V_lds[rv * 64 + ((ks * 32 + lk8) ^ sxk)];
                oacc[dt] = __builtin_amdgcn_mfma_f32_16x16x32_bf16(vb, pa, oacc[dt], 0, 0, 0);
            }
        }
        __builtin_amdgcn_s_setprio(0);

        if (nt < 31) {
            __syncthreads();
            const int nxt = cur ^ 1;
            #pragma unroll
            for (int it = 0; it < 4; ++it) {
                const int r = kr + it * 16;
                *(bf16x8*)&K_lds[nxt][r * 128 + (kc ^ ((r & 7) << 3))] = kreg[it];
                const int rv = vr + it * 32;
                *(bf16x8*)&V_lds[rv * 64 + (vc ^ ((rv & 7) << 3))] = vreg[it];
            }
            __syncthreads();
            cur ^= 1;
        }
    }

    ushort* Ob = O + ((size_t)bh * 1024 + m0 + w * 16 + l15) * 128;
    const float inv = 1.0f / lrun;
    #pragma unroll
    for (int dt = 0; dt < 8; ++dt) {
        ushort4 pk;
        #pragma unroll
        for (int r = 0; r < 4; ++r) (&pk.x)[r] = f2bf(oacc[dt][r] * inv);
        *(ushort4*)&Ob[dt * 16 + lr4] = pk;
    }
}

// ---------------------------------------------------------------------------
extern "C" void kernel_launch(void* const* d_in, const int* in_sizes, int n_in,
                              void* d_out, int out_size, void* d_ws, size_t ws_size,
                              hipStream_t stream)
{
    (void)in_sizes; (void)n_in; (void)out_size; (void)ws_size;
    const float* query = (const float*)d_in[0];
    const float* fts   = (const float*)d_in[1];
    const float* wqc = (const float*)d_in[2];
    const float* bqc = (const float*)d_in[3];
    const float* wq1 = (const float*)d_in[4];
    const float* bq1 = (const float*)d_in[5];
    const float* wq2 = (const float*)d_in[6];
    const float* bq2 = (const float*)d_in[7];
    const float* wk1 = (const float*)d_in[8];
    const float* bk1 = (const float*)d_in[9];
    const float* wk2 = (const float*)d_in[10];
    const float* bk2 = (const float*)d_in[11];
    const float* wv1 = (const float*)d_in[12];
    const float* bv1 = (const float*)d_in[13];
    const float* wv2 = (const float*)d_in[14];
    const float* bv2 = (const float*)d_in[15];
    const float* wo  = (const float*)d_in[16];
    const float* bo  = (const float*)d_in[17];
    const float* wf1 = (const float*)d_in[18];
    const float* bf1 = (const float*)d_in[19];
    const float* wf2 = (const float*)d_in[20];
    const float* bf2 = (const float*)d_in[21];
    float* out = (float*)d_out;

    // ws layout (~78 MB)
    char* ws = (char*)d_ws;
    ushort* ftb    = (ushort*)(ws + 0LL);          // 16 MB [32][2048][128]
    ushort* queryT = (ushort*)(ws + 16777216LL);   //  1 MB [4][1024][128]
    ushort* qbuf   = (ushort*)(ws + 26214400LL);   //  8 MB [32][1024][128]
    ushort* kbuf   = (ushort*)(ws + 34603008LL);   // 16 MB [32][2048][128]
    ushort* vbufT  = (ushort*)(ws + 51380224LL);   // 16 MB [32][128][2048]
    ushort* enh    = (ushort*)(ws + 68157440LL);   //  8 MB [32][1024][128]
    ushort* Wbf    = (ushort*)(ws + 76546048LL);   // 480 KB converted weights
    ushort* Wcomb  = (ushort*)(ws + 77299712LL);   // 256 KB [8][128][128]
    float*  bconst = (float*) (ws + 77561856LL);   // 512 B

    ushort* wf2_b = Wbf + 229376;

    // 1. prep: fragment/row converts + transposes + Wcomb + bconst
    prep_kernel<<<2206, 256, 0, stream>>>(
        wqc, wq1, wq2, wk1, wk2, wv1, wv2, wf2, query, fts, wo, wf1, bo, bf1,
        Wbf, queryT, ftb, Wcomb, bconst);
    // 2. q-path (fused 3-layer, fragment weights, no barriers)
    mlp3qfrag<<<256, 256, 0, stream>>>(queryT, Wbf, bqc, bq1, bq2, qbuf);
    // 3. k / v paths (fragment weights, no barriers)
    mlp2frag<false><<<512, 256, 0, stream>>>(ftb, Wbf + 163840, bk1,
                                             Wbf + 180224, bk2, kbuf);
    mlp2frag<true><<<512, 256, 0, stream>>>(ftb, Wbf + 196608, bv1,
                                            Wbf + 212992, bv2, vbufT);
    // 4. attention
    flash_attn_bf16<<<512, 256, 0, stream>>>(qbuf, kbuf, vbufT, enh);
    // 5. fused proj_out+concat+final MLP
    outpath2<<<128, 128, 0, stream>>>(enh, Wcomb, bconst, wf2_b, bf2, out);
}

// Round 14
// 181.378 us; speedup vs baseline: 1.9735x; 1.9735x over previous
//
#include <hip/hip_runtime.h>
#include <math.h>

typedef __attribute__((ext_vector_type(8))) __bf16 bf16x8;
typedef __attribute__((ext_vector_type(4))) float f32x4;
typedef __attribute__((ext_vector_type(4))) unsigned u32x4;

__device__ __forceinline__ float act_lrelu(float x) { return x >= 0.0f ? x : 0.01f * x; }
__device__ __forceinline__ float act_gelu(float x) { return 0.5f * x * (1.0f + erff(x * 0.7071067811865475f)); }
__device__ __forceinline__ ushort f2bf(float f) {
    unsigned u = __builtin_bit_cast(unsigned, f);
    u += 0x7fffu + ((u >> 16) & 1u);   // RTNE
    return (ushort)(u >> 16);
}
__device__ __forceinline__ unsigned pack2bf(float lo, float hi) {
    return (unsigned)f2bf(lo) | ((unsigned)f2bf(hi) << 16);
}

// ---------------------------------------------------------------------------
// swizzled-LDS MFMA helpers. W LDS layout: [128][128] ushort, element (r,c)
// stored at r*128 + (c ^ ((r&7)<<3)).
__device__ __forceinline__ void stage_wbf(const ushort* __restrict__ Wg,
                                          ushort* Wl, int tid)
{
    #pragma unroll
    for (int it = 0; it < 8; ++it) {
        const int lin = (tid + it * 256) * 8;
        const int r = lin >> 7, c = lin & 127;
        const bf16x8 v = *(const bf16x8*)&Wg[lin];
        *(bf16x8*)&Wl[r * 128 + (c ^ ((r & 7) << 3))] = v;
    }
}

__device__ __forceinline__ void layer8swz(const bf16x8 a[4], const ushort* Wl,
                                          f32x4 acc[8], int l15, int lk8)
{
    const int sx = (l15 & 7) << 3;
    #pragma unroll
    for (int ds = 0; ds < 4; ++ds) {
        const int cb = (ds * 32 + lk8) ^ sx;
        #pragma unroll
        for (int nt = 0; nt < 8; ++nt) {
            const bf16x8 b = *(const bf16x8*)&Wl[(nt * 16 + l15) * 128 + cb];
            acc[nt] = __builtin_amdgcn_mfma_f32_16x16x32_bf16(a[ds], b, acc[nt], 0, 0, 0);
        }
    }
}

template <int ACT>
__device__ __forceinline__ void retile_swz(const f32x4 acc[8], const float bias[8],
                                           ushort* tlw, int l15, int lr4, int lk8,
                                           bf16x8 aout[4])
{
    #pragma unroll
    for (int nt = 0; nt < 8; ++nt)
        #pragma unroll
        for (int j = 0; j < 4; ++j) {
            float v = acc[nt][j] + bias[nt];
            if constexpr (ACT == 1) v = act_lrelu(v);
            if constexpr (ACT == 2) v = act_gelu(v);
            const int row = lr4 + j;
            tlw[row * 128 + ((nt * 16 + l15) ^ ((row & 7) << 3))] = f2bf(v);
        }
    const int sx = (l15 & 7) << 3;
    #pragma unroll
    for (int ds = 0; ds < 4; ++ds)
        aout[ds] = *(const bf16x8*)&tlw[l15 * 128 + ((ds * 32 + lk8) ^ sx)];
}

// ---------------------------------------------------------------------------
// transpose helper: IN [bz][C][N] f32 tile (c0,n0) -> OUT [bz][N][C] bf16
__device__ __forceinline__ void transpose_tile(
    const float* __restrict__ IN, ushort* __restrict__ OUTb,
    int C, int N, int bx, int by, int bz, float (*T)[68], int tid)
{
    const int r = tid >> 4, c4 = (tid & 15) * 4;
    const int n0 = bx * 64, c0 = by * 64;
    const size_t ib = (size_t)bz * C * N;
    const size_t ob = (size_t)bz * N * C;
    #pragma unroll
    for (int p = 0; p < 4; ++p) {
        const int cl = r + p * 16;
        const float4 v = *(const float4*)&IN[ib + (size_t)(c0 + cl) * N + n0 + c4];
        *(float4*)&T[cl][c4] = v;
    }
    __syncthreads();
    #pragma unroll
    for (int p = 0; p < 4; ++p) {
        const int nl = r + p * 16;
        ushort4 u;
        u.x = f2bf(T[c4 + 0][nl]);
        u.y = f2bf(T[c4 + 1][nl]);
        u.z = f2bf(T[c4 + 2][nl]);
        u.w = f2bf(T[c4 + 3][nl]);
        *(ushort4*)&OUTb[ob + (size_t)(n0 + nl) * C + c0 + c4] = u;
    }
}

// ---------------------------------------------------------------------------
// prep: grid 2248, block 256.
//  blk 0..59     : convert square weights -> bf16 Wdst
//  blk 60..187   : queryT = query^T bf16   (128 blocks)
//  blk 188..195  : Wcomb_h = wf1_h @ wo via MFMA (wo transposed in-kernel)
//  blk 196..199  : bconst[j] = bf1[j] + sum_k wf1[j][k]*bo[k&127]
//  blk 200..2247 : ftb = fts^T bf16        (2048 blocks)
__global__ __launch_bounds__(256) void prep_kernel(
    const float* __restrict__ wqc, const float* __restrict__ wq1,
    const float* __restrict__ wq2, const float* __restrict__ wk1,
    const float* __restrict__ wk2, const float* __restrict__ wv1,
    const float* __restrict__ wv2, const float* __restrict__ wf2,
    const float* __restrict__ query, const float* __restrict__ fts,
    const float* __restrict__ wo, const float* __restrict__ wf1,
    const float* __restrict__ bo, const float* __restrict__ bf1,
    ushort* __restrict__ Wdst, ushort* __restrict__ queryT,
    ushort* __restrict__ ftb, ushort* __restrict__ Wcomb,
    float* __restrict__ bconst)
{
    __shared__ __align__(16) char sbuf[32768];
    const int tid = threadIdx.x;
    const int blk = blockIdx.x;

    if (blk < 60) {                       // weight convert
        #pragma unroll
        for (int p = 0; p < 4; ++p) {
            const int lin = blk * 4096 + p * 1024 + tid * 4;
            const float* s;
            if (lin < 131072) s = wqc + lin;
            else {
                const int m = (lin - 131072) >> 14, idx = (lin - 131072) & 16383;
                s = (m == 0) ? wq1 + idx : (m == 1) ? wq2 + idx : (m == 2) ? wk1 + idx :
                    (m == 3) ? wk2 + idx : (m == 4) ? wv1 + idx : (m == 5) ? wv2 + idx
                             : wf2 + idx;
            }
            const float4 v = *(const float4*)s;
            ushort4 u; u.x = f2bf(v.x); u.y = f2bf(v.y); u.z = f2bf(v.z); u.w = f2bf(v.w);
            *(ushort4*)&Wdst[lin] = u;
        }
    } else if (blk < 188) {               // queryT
        const int b2 = blk - 60;
        transpose_tile(query, queryT, 128, 1024, b2 & 15, (b2 >> 4) & 1, b2 >> 5,
                       (float(*)[68])sbuf, tid);
    } else if (blk < 196) {               // Wcomb via MFMA
        ushort* Wl = (ushort*)sbuf;
        const int h = blk - 188;
        const int lane = tid & 63, w = tid >> 6;
        const int l15 = lane & 15, lk8 = (lane >> 4) * 8, lr4 = (lane >> 4) * 4;
        #pragma unroll
        for (int it = 0; it < 16; ++it) {
            const int lin = (tid + it * 256) * 4;
            const int o = lin >> 7, d4 = lin & 127;
            const float4 v = *(const float4*)&wo[o * 128 + d4];
            #pragma unroll
            for (int j = 0; j < 4; ++j) {
                const int d = d4 + j;
                Wl[d * 128 + (o ^ ((d & 7) << 3))] = f2bf((&v.x)[j]);
            }
        }
        __syncthreads();
        const f32x4 z = {0.f, 0.f, 0.f, 0.f};
        #pragma unroll
        for (int rf = 0; rf < 2; ++rf) {
            const int row = w * 32 + rf * 16;
            bf16x8 a[4];
            #pragma unroll
            for (int ds = 0; ds < 4; ++ds) {
                const size_t base = (size_t)(row + l15) * 1024 + h * 128 + ds * 32 + lk8;
                const float4 lo = *(const float4*)&wf1[base];
                const float4 hi = *(const float4*)&wf1[base + 4];
                u32x4 wv;
                wv[0] = pack2bf(lo.x, lo.y); wv[1] = pack2bf(lo.z, lo.w);
                wv[2] = pack2bf(hi.x, hi.y); wv[3] = pack2bf(hi.z, hi.w);
                a[ds] = __builtin_bit_cast(bf16x8, wv);
            }
            f32x4 acc[8];
            #pragma unroll
            for (int i = 0; i < 8; ++i) acc[i] = z;
            layer8swz(a, Wl, acc, l15, lk8);
            #pragma unroll
            for (int nt = 0; nt < 8; ++nt)
                #pragma unroll
                for (int j = 0; j < 4; ++j)
                    Wcomb[h * 16384 + (row + lr4 + j) * 128 + nt * 16 + l15] =
                        f2bf(acc[nt][j]);
        }
    } else if (blk < 200) {               // bconst
        float* sm = (float*)sbuf;
        const int jl = tid >> 3, part = tid & 7;
        const int j = (blk - 196) * 32 + jl;
        float4 a4 = {0.f, 0.f, 0.f, 0.f};
        #pragma unroll
        for (int kk = 0; kk < 128; kk += 4) {
            const float4 wv = *(const float4*)&wf1[(size_t)j * 1024 + part * 128 + kk];
            const float4 bv = *(const float4*)&bo[kk];
            a4.x += wv.x * bv.x; a4.y += wv.y * bv.y;
            a4.z += wv.z * bv.z; a4.w += wv.w * bv.w;
        }
        sm[tid] = a4.x + a4.y + a4.z + a4.w;
        __syncthreads();
        if (part == 0) {
            float t = bf1[j];
            #pragma unroll
            for (int p2 = 0; p2 < 8; ++p2) t += sm[jl * 8 + p2];
            bconst[j] = t;
        }
    } else {                              // ftb
        const int b2 = blk - 200;
        transpose_tile(fts, ftb, 128, 2048, b2 & 31, (b2 >> 5) & 1, b2 >> 6,
                       (float(*)[68])sbuf, tid);
    }
}

// ---------------------------------------------------------------------------
// mlp1: Y = X @ W_head^T + B_head (no act). 128 rows/block, grid 256.
__global__ __launch_bounds__(256) void mlp1v(
    const ushort* __restrict__ X, const ushort* __restrict__ Wbf,
    const float* __restrict__ Bf, ushort* __restrict__ Y)
{
    __shared__ ushort Wl[128 * 128];
    const int tid = threadIdx.x, lane = tid & 63, w = tid >> 6;
    const int l15 = lane & 15, lk8 = (lane >> 4) * 8, lr4 = (lane >> 4) * 4;
    const int head = (blockIdx.x >> 3) & 7;
    stage_wbf(Wbf + head * 16384, Wl, tid);
    float b0[8];
    #pragma unroll
    for (int nt = 0; nt < 8; ++nt) b0[nt] = Bf[head * 128 + nt * 16 + l15];

    const int m0 = blockIdx.x * 128 + w * 32;
    bf16x8 a0[4], a1[4];
    #pragma unroll
    for (int ds = 0; ds < 4; ++ds) {
        int r0 = m0 + l15, r1 = m0 + 16 + l15;
        r0 = (r0 >> 13) * 1024 + (r0 & 1023);   // qh-space -> queryT-space
        r1 = (r1 >> 13) * 1024 + (r1 & 1023);
        a0[ds] = *(const bf16x8*)(X + (size_t)r0 * 128 + ds * 32 + lk8);
        a1[ds] = *(const bf16x8*)(X + (size_t)r1 * 128 + ds * 32 + lk8);
    }
    __syncthreads();
    const f32x4 z = {0.f, 0.f, 0.f, 0.f};
    #pragma unroll
    for (int rf = 0; rf < 2; ++rf) {
        f32x4 acc[8];
        #pragma unroll
        for (int i = 0; i < 8; ++i) acc[i] = z;
        layer8swz(rf ? a1 : a0, Wl, acc, l15, lk8);
        const int row = m0 + rf * 16;
        #pragma unroll
        for (int nt = 0; nt < 8; ++nt)
            #pragma unroll
            for (int j = 0; j < 4; ++j)
                Y[(size_t)(row + lr4 + j) * 128 + nt * 16 + l15] = f2bf(acc[nt][j] + b0[nt]);
    }
}

// ---------------------------------------------------------------------------
// mlp2dual: q/k/v 2-layer MLPs (lrelu -> gelu) in one launch. grid 1280.
//  blk 0..255  : q path (X=qh, wq1/wq2 -> qbuf)
//  blk 256..767: k path (X=ftb, wk1/wk2 -> kbuf)
//  blk 768..   : v path (X=ftb, wv1/wv2 -> vbufT, transposed write)
__global__ __launch_bounds__(256) void mlp2dual(
    const ushort* __restrict__ qh, const ushort* __restrict__ ftb,
    const ushort* __restrict__ Wbf,
    const float* __restrict__ bq1, const float* __restrict__ bq2,
    const float* __restrict__ bk1, const float* __restrict__ bk2,
    const float* __restrict__ bv1, const float* __restrict__ bv2,
    ushort* __restrict__ qbuf, ushort* __restrict__ kbuf,
    ushort* __restrict__ vbufT)
{
    __shared__ ushort W1l[128 * 128], W2l[128 * 128];
    __shared__ ushort tl[4][16 * 128];
    const int tid = threadIdx.x, lane = tid & 63, w = tid >> 6;
    const int l15 = lane & 15, lk8 = (lane >> 4) * 8, lr4 = (lane >> 4) * 4;
    const int blk = blockIdx.x;

    const ushort *X, *W1, *W2;
    const float *B1, *B2;
    ushort* Y;
    bool outt = false;
    int m0;
    if (blk < 256) {
        X = qh;  W1 = Wbf + 131072; W2 = Wbf + 147456; B1 = bq1; B2 = bq2;
        Y = qbuf;  m0 = blk * 128;
    } else if (blk < 768) {
        X = ftb; W1 = Wbf + 163840; W2 = Wbf + 180224; B1 = bk1; B2 = bk2;
        Y = kbuf;  m0 = (blk - 256) * 128;
    } else {
        X = ftb; W1 = Wbf + 196608; W2 = Wbf + 212992; B1 = bv1; B2 = bv2;
        Y = vbufT; m0 = (blk - 768) * 128; outt = true;
    }
    stage_wbf(W1, W1l, tid);
    stage_wbf(W2, W2l, tid);
    float b1[8], b2[8];
    #pragma unroll
    for (int nt = 0; nt < 8; ++nt) { b1[nt] = B1[nt * 16 + l15]; b2[nt] = B2[nt * 16 + l15]; }

    const int mw = m0 + w * 32;
    bf16x8 a0[4], a1[4];
    #pragma unroll
    for (int ds = 0; ds < 4; ++ds) {
        a0[ds] = *(const bf16x8*)(X + (size_t)(mw + l15) * 128 + ds * 32 + lk8);
        a1[ds] = *(const bf16x8*)(X + (size_t)(mw + 16 + l15) * 128 + ds * 32 + lk8);
    }
    __syncthreads();
    const f32x4 z = {0.f, 0.f, 0.f, 0.f};
    #pragma unroll
    for (int rf = 0; rf < 2; ++rf) {
        const int row = mw + rf * 16;
        f32x4 acc[8];
        #pragma unroll
        for (int i = 0; i < 8; ++i) acc[i] = z;
        layer8swz(rf ? a1 : a0, W1l, acc, l15, lk8);
        bf16x8 a2[4];
        retile_swz<1>(acc, b1, tl[w], l15, lr4, lk8, a2);
        f32x4 acc2[8];
        #pragma unroll
        for (int i = 0; i < 8; ++i) acc2[i] = z;
        layer8swz(a2, W2l, acc2, l15, lk8);
        if (!outt) {
            #pragma unroll
            for (int nt = 0; nt < 8; ++nt)
                #pragma unroll
                for (int j = 0; j < 4; ++j)
                    Y[(size_t)(row + lr4 + j) * 128 + nt * 16 + l15] =
                        f2bf(act_gelu(acc2[nt][j] + b2[nt]));
        } else {
            const int R0 = row + lr4;
            const int bh = R0 >> 11, key = R0 & 2047;
            #pragma unroll
            for (int nt = 0; nt < 8; ++nt) {
                ushort4 pk;
                #pragma unroll
                for (int j = 0; j < 4; ++j)
                    (&pk.x)[j] = f2bf(act_gelu(acc2[nt][j] + b2[nt]));
                *(ushort4*)&Y[((size_t)bh * 128 + nt * 16 + l15) * 2048 + key] = pk;
            }
        }
    }
}

// ---------------------------------------------------------------------------
// outpath: y = lrelu(sum_h enh_h @ Wcomb_h^T + bconst); out = lrelu(y@wf2^T+bf2)
__global__ __launch_bounds__(128) void outpath2(
    const ushort* __restrict__ E, const ushort* __restrict__ Wcomb,
    const float* __restrict__ bconst, const ushort* __restrict__ Wf2bf,
    const float* __restrict__ Bf2, float* __restrict__ OUT)
{
    __shared__ ushort Wc[128 * 128], W2l[128 * 128];
    __shared__ ushort tl[2][16 * 128];
    const int tid = threadIdx.x, lane = tid & 63, w = tid >> 6;
    const int l15 = lane & 15, lk8 = (lane >> 4) * 8, lr4 = (lane >> 4) * 4;
    const int b = blockIdx.x >> 5;
    const int m0 = (blockIdx.x & 31) * 32;

    #pragma unroll
    for (int it = 0; it < 16; ++it) {
        const int lin = (tid + it * 128) * 8;
        const int r = lin >> 7, c = lin & 127;
        *(bf16x8*)&W2l[r * 128 + (c ^ ((r & 7) << 3))] = *(const bf16x8*)&Wf2bf[lin];
    }
    float bc[8], b2[8];
    #pragma unroll
    for (int nt = 0; nt < 8; ++nt) { bc[nt] = bconst[nt * 16 + l15]; b2[nt] = Bf2[nt * 16 + l15]; }

    const f32x4 z = {0.f, 0.f, 0.f, 0.f};
    f32x4 yacc[8];
    #pragma unroll
    for (int i = 0; i < 8; ++i) yacc[i] = z;

    bf16x8 a[4], an[4], wreg[16];
    auto loadE = [&](int h, bf16x8 dst[4]) {
        const size_t er = ((size_t)((b * 8 + h) * 1024) + m0 + w * 16 + l15) * 128;
        #pragma unroll
        for (int ds = 0; ds < 4; ++ds) dst[ds] = *(const bf16x8*)(E + er + ds * 32 + lk8);
    };
    auto wload = [&](int h) {
        #pragma unroll
        for (int it = 0; it < 16; ++it)
            wreg[it] = *(const bf16x8*)&Wcomb[h * 16384 + (tid + it * 128) * 8];
    };
    auto wwrite = [&]() {
        #pragma unroll
        for (int it = 0; it < 16; ++it) {
            const int lin = (tid + it * 128) * 8;
            const int r = lin >> 7, c = lin & 127;
            *(bf16x8*)&Wc[r * 128 + (c ^ ((r & 7) << 3))] = wreg[it];
        }
    };

    wload(0); wwrite();
    loadE(0, a);
    for (int h = 0; h < 8; ++h) {
        if (h < 7) { wload(h + 1); loadE(h + 1, an); }
        __syncthreads();
        layer8swz(a, Wc, yacc, l15, lk8);
        __syncthreads();
        if (h < 7) {
            wwrite();
            #pragma unroll
            for (int ds = 0; ds < 4; ++ds) a[ds] = an[ds];
        }
    }
    bf16x8 a3[4];
    retile_swz<1>(yacc, bc, tl[w], l15, lr4, lk8, a3);
    f32x4 oacc[8];
    #pragma unroll
    for (int i = 0; i < 8; ++i) oacc[i] = z;
    layer8swz(a3, W2l, oacc, l15, lk8);
    #pragma unroll
    for (int nt = 0; nt < 8; ++nt)
        #pragma unroll
        for (int j = 0; j < 4; ++j)
            OUT[((size_t)b * 1024 + m0 + w * 16 + lr4 + j) * 128 + nt * 16 + l15] =
                act_lrelu(oacc[nt][j] + b2[nt]);
}

// ---------------------------------------------------------------------------
// bf16 MFMA flash attention v4: swapped operands, in-register softmax,
// XOR-swizzled LDS (no pads), K double-buffered, V single-buffered.
// LDS = 48 KB. grid 512 (XCD decode), block 256.
__global__ __launch_bounds__(256, 3) void flash_attn_bf16(
    const ushort* __restrict__ Q, const ushort* __restrict__ Kx,
    const ushort* __restrict__ Vt, ushort* __restrict__ O)
{
    constexpr float SCALE = 0.08838834764831845f;
    const int bid = blockIdx.x;
    const int bh = (bid & 7) * 4 + ((bid >> 3) & 3);
    const int m0 = (bid >> 5) * 64;
    const int tid = threadIdx.x;
    const int lane = tid & 63, w = tid >> 6;
    const int l15 = lane & 15, g = lane >> 4;
    const int lk8 = g * 8, lr4 = g * 4;
    const int sxk = (l15 & 7) << 3;
    const int sel = g >> 1;
    const int src0 = l15 + ((lane & 16) << 1);

    __shared__ ushort K_lds[2][64 * 128];
    __shared__ ushort V_lds[128 * 64];

    const ushort* Qb = Q + (size_t)bh * 1024 * 128;
    const ushort* Kb = Kx + (size_t)bh * 2048 * 128;
    const ushort* Vb = Vt + (size_t)bh * 128 * 2048;

    bf16x8 qf[4];
    {
        const int row = m0 + w * 16 + l15;
        #pragma unroll
        for (int ds = 0; ds < 4; ++ds)
            qf[ds] = *(const bf16x8*)(Qb + (size_t)row * 128 + ds * 32 + lk8);
    }

    const int kr = tid >> 4, kc = (tid & 15) * 8;
    const int vr = tid >> 3, vc = (tid & 7) * 8;
    bf16x8 kreg[4], vreg[4];
    #pragma unroll
    for (int it = 0; it < 4; ++it) {
        kreg[it] = *(const bf16x8*)(Kb + (size_t)(kr + it * 16) * 128 + kc);
        vreg[it] = *(const bf16x8*)(Vb + (size_t)(vr + it * 32) * 2048 + vc);
    }
    #pragma unroll
    for (int it = 0; it < 4; ++it) {
        const int r = kr + it * 16;
        *(bf16x8*)&K_lds[0][r * 128 + (kc ^ ((r & 7) << 3))] = kreg[it];
        const int rv = vr + it * 32;
        *(bf16x8*)&V_lds[rv * 64 + (vc ^ ((rv & 7) << 3))] = vreg[it];
    }
    __syncthreads();

    f32x4 oacc[8];
    #pragma unroll
    for (int i = 0; i < 8; ++i) oacc[i] = f32x4{0.f, 0.f, 0.f, 0.f};
    float mrun = -1e30f, lrun = 0.f;
    int cur = 0;

    for (int nt = 0; nt < 32; ++nt) {
        if (nt < 31) {
            const int n1 = (nt + 1) * 64;
            #pragma unroll
            for (int it = 0; it < 4; ++it) {
                kreg[it] = *(const bf16x8*)(Kb + (size_t)(n1 + kr + it * 16) * 128 + kc);
                vreg[it] = *(const bf16x8*)(Vb + (size_t)(vr + it * 32) * 2048 + n1 + vc);
            }
        }
        const ushort* Kc = &K_lds[cur][0];

        f32x4 s[4];
        #pragma unroll
        for (int i = 0; i < 4; ++i) s[i] = f32x4{0.f, 0.f, 0.f, 0.f};
        __builtin_amdgcn_s_setprio(1);
        #pragma unroll
        for (int ds = 0; ds < 4; ++ds)
            #pragma unroll
            for (int ct = 0; ct < 4; ++ct) {
                const bf16x8 kf = *(const bf16x8*)
                    &Kc[(ct * 16 + l15) * 128 + ((ds * 32 + lk8) ^ sxk)];
                s[ct] = __builtin_amdgcn_mfma_f32_16x16x32_bf16(kf, qf[ds], s[ct], 0, 0, 0);
            }
        __builtin_amdgcn_s_setprio(0);

        float mx = fmaxf(fmaxf(fmaxf(s[0][0], s[0][1]), fmaxf(s[0][2], s[0][3])),
                         fmaxf(fmaxf(s[1][0], s[1][1]), fmaxf(s[1][2], s[1][3])));
        mx = fmaxf(mx, fmaxf(fmaxf(fmaxf(s[2][0], s[2][1]), fmaxf(s[2][2], s[2][3])),
                             fmaxf(fmaxf(s[3][0], s[3][1]), fmaxf(s[3][2], s[3][3]))));
        mx *= SCALE;
        mx = fmaxf(mx, __shfl_xor(mx, 16));
        mx = fmaxf(mx, __shfl_xor(mx, 32));

        if (!__all((int)(mx <= mrun + 8.f))) {
            const float mnew = fmaxf(mrun, mx);
            const float fsc = __expf(mrun - mnew);
            mrun = mnew;
            lrun *= fsc;
            #pragma unroll
            for (int dt = 0; dt < 8; ++dt)
                #pragma unroll
                for (int j = 0; j < 4; ++j)
                    oacc[dt][j] *= fsc;
        }

        float p[4][4];
        float sum = 0.f;
        #pragma unroll
        for (int ct = 0; ct < 4; ++ct)
            #pragma unroll
            for (int r = 0; r < 4; ++r) {
                const float e = __expf(s[ct][r] * SCALE - mrun);
                p[ct][r] = e;
                sum += e;
            }
        sum += __shfl_xor(sum, 16);
        sum += __shfl_xor(sum, 32);
        lrun += sum;

        unsigned P2[4][2];
        #pragma unroll
        for (int ct = 0; ct < 4; ++ct) {
            P2[ct][0] = pack2bf(p[ct][0], p[ct][1]);
            P2[ct][1] = pack2bf(p[ct][2], p[ct][3]);
        }

        __builtin_amdgcn_s_setprio(1);
        #pragma unroll
        for (int ks = 0; ks < 2; ++ks) {
            u32x4 wv;
            #pragma unroll
            for (int t = 0; t < 4; ++t) {
                const int src = src0 + ((t >> 1) << 4);
                const unsigned wa = __shfl(P2[ks * 2 + 0][t & 1], src);
                const unsigned wb = __shfl(P2[ks * 2 + 1][t & 1], src);
                wv[t] = sel ? wb : wa;
            }
            const bf16x8 pa = __builtin_bit_cast(bf16x8, wv);
            #pragma unroll
            for (int dt = 0; dt < 8; ++dt) {
                const int rv = dt * 16 + l15;
                const bf16x8 vb = *(const bf16x8*)
                    &V_lds[rv * 64 + ((ks * 32 + lk8) ^ sxk)];
                oacc[dt] = __builtin_amdgcn_mfma_f32_16x16x32_bf16(vb, pa, oacc[dt], 0, 0, 0);
            }
        }
        __builtin_amdgcn_s_setprio(0);

        if (nt < 31) {
            __syncthreads();
            const int nxt = cur ^ 1;
            #pragma unroll
            for (int it = 0; it < 4; ++it) {
                const int r = kr + it * 16;
                *(bf16x8*)&K_lds[nxt][r * 128 + (kc ^ ((r & 7) << 3))] = kreg[it];
                const int rv = vr + it * 32;
                *(bf16x8*)&V_lds[rv * 64 + (vc ^ ((rv & 7) << 3))] = vreg[it];
            }
            __syncthreads();
            cur ^= 1;
        }
    }

    ushort* Ob = O + ((size_t)bh * 1024 + m0 + w * 16 + l15) * 128;
    const float inv = 1.0f / lrun;
    #pragma unroll
    for (int dt = 0; dt < 8; ++dt) {
        ushort4 pk;
        #pragma unroll
        for (int r = 0; r < 4; ++r) (&pk.x)[r] = f2bf(oacc[dt][r] * inv);
        *(ushort4*)&Ob[dt * 16 + lr4] = pk;
    }
}

// ---------------------------------------------------------------------------
extern "C" void kernel_launch(void* const* d_in, const int* in_sizes, int n_in,
                              void* d_out, int out_size, void* d_ws, size_t ws_size,
                              hipStream_t stream)
{
    (void)in_sizes; (void)n_in; (void)out_size; (void)ws_size;
    const float* query = (const float*)d_in[0];
    const float* fts   = (const float*)d_in[1];
    const float* wqc = (const float*)d_in[2];
    const float* bqc = (const float*)d_in[3];
    const float* wq1 = (const float*)d_in[4];
    const float* bq1 = (const float*)d_in[5];
    const float* wq2 = (const float*)d_in[6];
    const float* bq2 = (const float*)d_in[7];
    const float* wk1 = (const float*)d_in[8];
    const float* bk1 = (const float*)d_in[9];
    const float* wk2 = (const float*)d_in[10];
    const float* bk2 = (const float*)d_in[11];
    const float* wv1 = (const float*)d_in[12];
    const float* bv1 = (const float*)d_in[13];
    const float* wv2 = (const float*)d_in[14];
    const float* bv2 = (const float*)d_in[15];
    const float* wo  = (const float*)d_in[16];
    const float* bo  = (const float*)d_in[17];
    const float* wf1 = (const float*)d_in[18];
    const float* bf1 = (const float*)d_in[19];
    const float* wf2 = (const float*)d_in[20];
    const float* bf2 = (const float*)d_in[21];
    float* out = (float*)d_out;

    // ws layout (~78 MB)
    char* ws = (char*)d_ws;
    ushort* ftb    = (ushort*)(ws + 0LL);          // 16 MB [32][2048][128]
    ushort* queryT = (ushort*)(ws + 16777216LL);   //  1 MB [4][1024][128]
    ushort* qh     = (ushort*)(ws + 17825792LL);   //  8 MB [32][1024][128]
    ushort* qbuf   = (ushort*)(ws + 26214400LL);   //  8 MB [32][1024][128]
    ushort* kbuf   = (ushort*)(ws + 34603008LL);   // 16 MB [32][2048][128]
    ushort* vbufT  = (ushort*)(ws + 51380224LL);   // 16 MB [32][128][2048]
    ushort* enh    = (ushort*)(ws + 68157440LL);   //  8 MB [32][1024][128]
    ushort* Wbf    = (ushort*)(ws + 76546048LL);   // 480 KB converted weights
    ushort* Wcomb  = (ushort*)(ws + 77299712LL);   // 256 KB [8][128][128]
    float*  bconst = (float*) (ws + 77561856LL);   // 512 B

    ushort* wqc_b = Wbf + 0;
    ushort* wf2_b = Wbf + 229376;

    // 1. prep: converts + transposes + Wcomb + bconst (one launch)
    prep_kernel<<<2248, 256, 0, stream>>>(
        wqc, wq1, wq2, wk1, wk2, wv1, wv2, wf2, query, fts, wo, wf1, bo, bf1,
        Wbf, queryT, ftb, Wcomb, bconst);
    // 2. q-conv
    mlp1v<<<256, 256, 0, stream>>>(queryT, wqc_b, bqc, qh);
    // 3. q/k/v MLPs in one launch
    mlp2dual<<<1280, 256, 0, stream>>>(qh, ftb, Wbf, bq1, bq2, bk1, bk2,
                                       bv1, bv2, qbuf, kbuf, vbufT);
    // 4. attention
    flash_attn_bf16<<<512, 256, 0, stream>>>(qbuf, kbuf, vbufT, enh);
    // 5. fused proj_out+concat+final MLP
    outpath2<<<128, 128, 0, stream>>>(enh, Wcomb, bconst, wf2_b, bf2, out);
}